// Round 8
// baseline (154.509 us; speedup 1.0000x reference)
//
#include <hip/hip_runtime.h>

#define M_TOK 1024
#define NOUT  4096
#define KIN   4096

typedef __attribute__((ext_vector_type(8))) short bf16x8_t;
typedef __attribute__((ext_vector_type(4))) float f32x4_t;

// workspace layout:
//   Bfrag  2 MB @ 0        (bit-bytes in MFMA B-frag order, u16 per (n16,kt,l))
//   Xfrag  8 MB @ 4 MB     (bf16 x in MFMA A-frag order)
// B kept at u16/2MB: per-XCD L2 working set = A band (1MB) + B (2MB) = 3MB < 4MB.

// ---- fp32 -> bf16 RNE pack (known-good) ----
__device__ __forceinline__ unsigned pack_bf16(float a, float b) {
  unsigned ua = __float_as_uint(a);
  unsigned ub = __float_as_uint(b);
  ua = (ua + 0x7FFFu + ((ua >> 16) & 1u)) >> 16;
  ub = (ub + 0x7FFFu + ((ub >> 16) & 1u)) >> 16;
  return ua | (ub << 16);
}

__device__ __forceinline__ unsigned bits8(float4 a, float4 b) {
  return  (unsigned)(a.x > 0.f)        | ((unsigned)(a.y > 0.f) << 1) |
         ((unsigned)(a.z > 0.f) << 2)  | ((unsigned)(a.w > 0.f) << 3) |
         ((unsigned)(b.x > 0.f) << 4)  | ((unsigned)(b.y > 0.f) << 5) |
         ((unsigned)(b.z > 0.f) << 6)  | ((unsigned)(b.w > 0.f) << 7);
}

// async global -> LDS, 16B per lane. LDS dest is wave-uniform base; HW writes
// base + lane*16 (guide §5 / m97). Src is per-lane.
__device__ __forceinline__ void gload_lds16(const uint4* g, uint4* l) {
  __builtin_amdgcn_global_load_lds(
      (const __attribute__((address_space(1))) unsigned*)g,
      (__attribute__((address_space(3))) unsigned*)l, 16, 0, 0);
}

// ---- prep v6 (verified best): pure streaming, no ballot/LDS/sync.
// Blocks 0..4095 = W -> Bfrag (thread t emits u16 t; exact prep_w2 semantics).
// Blocks 4096..6143 = X -> Xfrag (known-good).
__global__ __launch_bounds__(256) void prep_wx(const float4* __restrict__ w4,
                                               unsigned short* __restrict__ bfrag,
                                               const float4* __restrict__ x4,
                                               uint4* __restrict__ xfrag) {
  const unsigned bb = blockIdx.x;
  if (bb < 4096) {
    const unsigned t = bb * 256 + threadIdx.x;        // 1,048,576 outputs
    const int l16 = t & 15, quad = (t >> 4) & 3;
    const int kt = (t >> 6) & 63, n16 = t >> 12;
    const int n = n16 * 16 + l16;
    const float4* p = w4 + (size_t)n * (KIN / 4) + kt * 16 + quad * 2;
    float4 f0 = p[0], f1 = p[1];      // cols c0 .. c0+7
    float4 f2 = p[8], f3 = p[9];      // cols c0+32 .. c0+39
    const unsigned b0 = bits8(f0, f1);
    const unsigned b1 = bits8(f2, f3);
    bfrag[t] = (unsigned short)(b0 | (b1 << 8));
  } else {
    const unsigned t = (bb - 4096) * 256 + threadIdx.x;  // 524,288 total
    const int l = t & 63;
    const unsigned f = t >> 6;
    const int m16 = f >> 7, k32 = f & 127;
    const int row = m16 * 16 + (l & 15);
    const int c4  = k32 * 8 + (l >> 4) * 2;
    const float4* p = x4 + (size_t)row * (KIN / 4) + c4;
    float4 a = p[0], b = p[1];
    uint4 o;
    o.x = pack_bf16(a.x, a.y);
    o.y = pack_bf16(a.z, a.w);
    o.z = pack_bf16(b.x, b.y);
    o.w = pack_bf16(b.z, b.w);
    xfrag[t] = o;
  }
}

// ---- GEMM v8: LDS-staged A. Theory (validated by v1/v4/v5/v7 invariance):
// the kernel was L1-BW-bound -- each wave re-read the block's A slice through
// L1 (4.2 MB/CU at ~64B/cyc ~= 27us). Now each A byte crosses L1 ONCE per
// block via global_load_lds (width 16, no VGPR roundtrip), waves read it from
// LDS. Wave tile 32m x 64n (i=2, j=4): LDS-read per CU = 8192KB/j = 2.05MB
// (~10us) < MFMA floor 16.6us. Expansion = verified 3-op 2.0-encoding (x0.5
// in epilogue) to keep VALU under the MFMA floor at j=4.
// Block 64m x 128n, grid 512, XCD swizzle, L2 set 3MB/XCD -- all unchanged.
// Schedule: double-buffered 16KB LDS (2 kt per stage), stage(next) issued
// before compute(cur), one __syncthreads (vmcnt-drain + barrier) per K=64.
__global__ __launch_bounds__(256, 2) void gemm_bin_kernel(
    const unsigned short* __restrict__ Xf,
    const unsigned short* __restrict__ Bf,
    const float* __restrict__ sf,
    float* __restrict__ C) {
  __shared__ uint4 lds[2][4][4][64];              // [buf][m16i][h][lane] 32 KB
  const int tid  = threadIdx.x;
  const int lane = tid & 63;
  const int wave = tid >> 6;                      // 0..3
  const int wm   = wave >> 1;                     // m-half (32 rows)
  const int wq   = wave & 1;                      // n-quarter pair (64 cols)
  const int quad = lane >> 4;
  const int l16  = lane & 15;
  const unsigned bid = blockIdx.x;
  const int xcd = bid & 7, idx = bid >> 3;        // idx 0..63
  const int m0 = (xcd * 2 + (idx >> 5)) * 64;     // 16 m-bands, 2 per XCD
  const int n0 = (idx & 31) * 128;                // 32 n-tiles per band
  const int m16b = m0 >> 4;
  const int n16b = (n0 >> 4) + wq * 4;            // 4 n16 tiles per wave

  const uint4* Xf4 = (const uint4*)Xf;

  f32x4_t acc[2][4];
#pragma unroll
  for (int i = 0; i < 2; ++i)
#pragma unroll
    for (int j = 0; j < 4; ++j)
      acc[i][j] = (f32x4_t){0.f, 0.f, 0.f, 0.f};

  // stage 2 kt (16 KB): wave w copies m16 tile (m16b+w), h = it*4 .. +3
  auto STAGE = [&](uint4 (&L)[4][4][64], int it) {
    const uint4* src = Xf4 + ((size_t)(m16b + wave) * 128 + it * 4) * 64 + lane;
#pragma unroll
    for (int q = 0; q < 4; ++q)
      gload_lds16(src + q * 64, &L[wave][q][0]);
  };

  // B: j=4 x 2kt u16 words per iteration (direct global; L2-resident, tiny)
  auto LOADB = [&](unsigned (&bb)[2][4], int it) {
#pragma unroll
    for (int s = 0; s < 2; ++s)
#pragma unroll
      for (int j = 0; j < 4; ++j)
        bb[s][j] = (unsigned)Bf[((n16b + j) * 64 + it * 2 + s) * 64 + lane];
  };

  auto READA = [&](uint4 (&af)[2][4], const uint4 (&L)[4][4][64]) {
#pragma unroll
    for (int i = 0; i < 2; ++i)
#pragma unroll
      for (int h = 0; h < 4; ++h)
        af[i][h] = L[wm * 2 + i][h][lane];
  };

  auto COMP = [&](const uint4 (&af)[2][4], const unsigned (&bb)[2][4]) {
#pragma unroll
    for (int s = 0; s < 2; ++s)
#pragma unroll
      for (int j = 0; j < 4; ++j) {
        const unsigned br = bb[s][j];   // zero-extended u16: no garbage bits
#pragma unroll
        for (int ks = 0; ks < 2; ++ks) {
          union { unsigned u32[4]; bf16x8_t v; } ex;
#pragma unroll
          for (int p = 0; p < 4; ++p)
            ex.u32[p] = ((br << (14 - 8 * ks - 2 * p)) |
                         (br << (29 - 8 * ks - 2 * p))) & 0x40004000u;
#pragma unroll
          for (int i = 0; i < 2; ++i) {
            union { uint4 q; bf16x8_t v; } av;
            av.q = af[i][s * 2 + ks];
            acc[i][j] = __builtin_amdgcn_mfma_f32_16x16x32_bf16(av.v, ex.v, acc[i][j], 0, 0, 0);
          }
        }
      }
  };

  unsigned bA[2][4], bB[2][4];
  uint4 af[2][4];

  STAGE(lds[0], 0);
  LOADB(bA, 0);
  __syncthreads();                      // drain stage 0, all waves ready

  for (int it = 0; it < 32; it += 2) {
    // ---- even half: compute lds[0]/bA, stage lds[1] for it+1 ----
    if (it + 1 < 32) { STAGE(lds[1], it + 1); LOADB(bB, it + 1); }
    READA(af, lds[0]);
    COMP(af, bA);
    __syncthreads();                    // stage(it+1) done; lds[0] free
    // ---- odd half: compute lds[1]/bB, stage lds[0] for it+2 ----
    if (it + 2 < 32) { STAGE(lds[0], it + 2); LOADB(bA, it + 2); }
    READA(af, lds[1]);
    COMP(af, bB);
    __syncthreads();                    // stage(it+2) done; lds[1] free
  }

  // epilogue: C/D layout col = lane&15, row = quad*4 + reg.
  // *0.5f compensates the 2.0 bit-encoding (exact, power of two).
#pragma unroll
  for (int j = 0; j < 4; ++j) {
    const int n = n0 + wq * 64 + j * 16 + l16;
    const float s = rintf(fmaxf(sf[n], 1.0f)) * 0.5f;
#pragma unroll
    for (int i = 0; i < 2; ++i) {
      const int mr = m0 + wm * 32 + i * 16 + quad * 4;
#pragma unroll
      for (int r = 0; r < 4; ++r)
        C[(size_t)(mr + r) * NOUT + n] = acc[i][j][r] * s;
    }
  }
}

extern "C" void kernel_launch(void* const* d_in, const int* in_sizes, int n_in,
                              void* d_out, int out_size, void* d_ws, size_t ws_size,
                              hipStream_t stream) {
  const float* x  = (const float*)d_in[0];  // [1024][4096]
  const float* w  = (const float*)d_in[1];  // [4096][4096]
  const float* sf = (const float*)d_in[2];  // [4096]
  float* out = (float*)d_out;               // [1024][4096]

  unsigned short* Bfrag = (unsigned short*)d_ws;                        // 2 MB
  unsigned short* Xfrag = (unsigned short*)((char*)d_ws + (4u << 20));  // 8 MB

  prep_wx<<<6144, 256, 0, stream>>>((const float4*)w, Bfrag, (const float4*)x,
                                    (uint4*)Xfrag);
  gemm_bin_kernel<<<512, 256, 0, stream>>>(Xfrag, Bfrag, sf, out);
}

// Round 9
// 141.389 us; speedup vs baseline: 1.0928x; 1.0928x over previous
//
#include <hip/hip_runtime.h>

#define M_TOK 1024
#define NOUT  4096
#define KIN   4096

typedef __attribute__((ext_vector_type(8))) short bf16x8_t;
typedef __attribute__((ext_vector_type(4))) float f32x4_t;

// workspace layout:
//   Bfrag  2 MB @ 0        (bit-bytes in MFMA B-frag order, u16 per (n16,kt,l))
//   Xfrag  8 MB @ 4 MB     (bf16 x in MFMA A-frag order)
// Per-XCD L2 working set: A band-pair (1MB) + B (2MB) = 3MB < 4MB (v1-proven).

// ---- fp32 -> bf16 RNE pack (known-good) ----
__device__ __forceinline__ unsigned pack_bf16(float a, float b) {
  unsigned ua = __float_as_uint(a);
  unsigned ub = __float_as_uint(b);
  ua = (ua + 0x7FFFu + ((ua >> 16) & 1u)) >> 16;
  ub = (ub + 0x7FFFu + ((ub >> 16) & 1u)) >> 16;
  return ua | (ub << 16);
}

__device__ __forceinline__ unsigned bits8(float4 a, float4 b) {
  return  (unsigned)(a.x > 0.f)        | ((unsigned)(a.y > 0.f) << 1) |
         ((unsigned)(a.z > 0.f) << 2)  | ((unsigned)(a.w > 0.f) << 3) |
         ((unsigned)(b.x > 0.f) << 4)  | ((unsigned)(b.y > 0.f) << 5) |
         ((unsigned)(b.z > 0.f) << 6)  | ((unsigned)(b.w > 0.f) << 7);
}

// ---- prep v6 (verified best): pure streaming, no ballot/LDS/sync.
// Blocks 0..4095 = W -> Bfrag (thread t emits u16 t; exact prep_w2 semantics).
// Blocks 4096..6143 = X -> Xfrag (known-good).
__global__ __launch_bounds__(256) void prep_wx(const float4* __restrict__ w4,
                                               unsigned short* __restrict__ bfrag,
                                               const float4* __restrict__ x4,
                                               uint4* __restrict__ xfrag) {
  const unsigned bb = blockIdx.x;
  if (bb < 4096) {
    const unsigned t = bb * 256 + threadIdx.x;        // 1,048,576 outputs
    const int l16 = t & 15, quad = (t >> 4) & 3;
    const int kt = (t >> 6) & 63, n16 = t >> 12;
    const int n = n16 * 16 + l16;
    const float4* p = w4 + (size_t)n * (KIN / 4) + kt * 16 + quad * 2;
    float4 f0 = p[0], f1 = p[1];      // cols c0 .. c0+7
    float4 f2 = p[8], f3 = p[9];      // cols c0+32 .. c0+39
    const unsigned b0 = bits8(f0, f1);
    const unsigned b1 = bits8(f2, f3);
    bfrag[t] = (unsigned short)(b0 | (b1 << 8));
  } else {
    const unsigned t = (bb - 4096) * 256 + threadIdx.x;  // 524,288 total
    const int l = t & 63;
    const unsigned f = t >> 6;
    const int m16 = f >> 7, k32 = f & 127;
    const int row = m16 * 16 + (l & 15);
    const int c4  = k32 * 8 + (l >> 4) * 2;
    const float4* p = x4 + (size_t)row * (KIN / 4) + c4;
    float4 a = p[0], b = p[1];
    uint4 o;
    o.x = pack_bf16(a.x, a.y);
    o.y = pack_bf16(a.z, a.w);
    o.z = pack_bf16(b.x, b.y);
    o.w = pack_bf16(b.z, b.w);
    xfrag[t] = o;
  }
}

// ---- GEMM v9: j=4 (wave 64m x 64n) halves L1 A-traffic per FLOP -- the
// quantity that was invariant (and ~27us at 64B/cyc) across v1/v5/v7's
// identical 45us results. No LDS staging in the main loop (v8's 32 vmcnt-
// drain barriers cost more than L1 relief gained). Wave count restored to
// 2/SIMD via the v7-verified in-block K-split: waves 0-3 = K[0,2048),
// waves 4-7 = K[2048,4096); single end-of-kernel LDS reduction (64KB).
// Block 64m x 256n (all 8 waves share one m-band -> L1 dedup), grid 256
// (1 block/CU), XCD swizzle as v1, 2-deep prefetch, 3-op 2.0-encoding
// (x0.5 in epilogue; correctness verified v5/v8).
__global__ __launch_bounds__(512, 2) void gemm_bin_kernel(
    const unsigned short* __restrict__ Xf,
    const unsigned short* __restrict__ Bf,
    const float* __restrict__ sf,
    float* __restrict__ C) {
  __shared__ f32x4_t red[4][16][64];              // 64 KB, used once at end
  const int tid  = threadIdx.x;
  const int lane = tid & 63;
  const int wave = tid >> 6;                      // 0..7
  const int wsub = wave & 3;                      // n-quadrant (64 cols each)
  const int kh   = wave >> 2;                     // k-half
  const int quad = lane >> 4;
  const int l16  = lane & 15;
  const unsigned bid = blockIdx.x;                // 256 blocks
  const int xcd = bid & 7, idx = bid >> 3;        // idx 0..31
  const int m0 = (xcd * 2 + (idx >> 4)) * 64;     // 16 m-bands, 2 per XCD
  const int n0 = (idx & 15) * 256;                // 16 n-slabs
  const int m16b = m0 >> 4;                       // 4 m16 tiles (shared by all waves)
  const int n16b = (n0 >> 4) + wsub * 4;          // 4 n16 tiles per wave

  const uint4* Xf4 = (const uint4*)Xf;

  f32x4_t acc[4][4];
#pragma unroll
  for (int i = 0; i < 4; ++i)
#pragma unroll
    for (int j = 0; j < 4; ++j)
      acc[i][j] = (f32x4_t){0.f, 0.f, 0.f, 0.f};

  uint4 a[2][4][2];      // [buf][i][ks]
  unsigned b[2][4];      // [buf][j]

  auto LOAD = [&](int u, int ktl) {
    const int kt = kh * 32 + ktl;                 // global k-tile 0..63 (64 k each)
#pragma unroll
    for (int i = 0; i < 4; ++i)
#pragma unroll
      for (int ks = 0; ks < 2; ++ks)
        a[u][i][ks] = Xf4[((size_t)(m16b + i) * 128 + kt * 2 + ks) * 64 + lane];
#pragma unroll
    for (int j = 0; j < 4; ++j)
      b[u][j] = (unsigned)Bf[((n16b + j) * 64 + kt) * 64 + lane];
  };

  auto COMP = [&](int u) {
#pragma unroll
    for (int j = 0; j < 4; ++j)
#pragma unroll
      for (int ks = 0; ks < 2; ++ks) {
        const unsigned br = b[u][j];   // zero-extended u16: no garbage bits
        union { unsigned u32[4]; bf16x8_t v; } ex;
#pragma unroll
        for (int p = 0; p < 4; ++p)
          ex.u32[p] = ((br << (14 - 8 * ks - 2 * p)) |
                       (br << (29 - 8 * ks - 2 * p))) & 0x40004000u;
#pragma unroll
        for (int i = 0; i < 4; ++i) {
          union { uint4 q; bf16x8_t v; } av;
          av.q = a[u][i][ks];
          acc[i][j] = __builtin_amdgcn_mfma_f32_16x16x32_bf16(av.v, ex.v, acc[i][j], 0, 0, 0);
        }
      }
  };

  LOAD(0, 0);
  for (int ktl = 0; ktl < 32; ktl += 2) {
    LOAD(1, ktl + 1);
    COMP(0);
    if (ktl + 2 < 32) LOAD(0, ktl + 2);
    COMP(1);
  }

  // ---- pairwise K reduction through LDS (contiguous 16B/lane) ----
  if (kh == 1) {
#pragma unroll
    for (int i = 0; i < 4; ++i)
#pragma unroll
      for (int j = 0; j < 4; ++j)
        red[wsub][i * 4 + j][lane] = acc[i][j];
  }
  __syncthreads();
  if (kh == 0) {
#pragma unroll
    for (int i = 0; i < 4; ++i)
#pragma unroll
      for (int j = 0; j < 4; ++j)
        acc[i][j] += red[wsub][i * 4 + j][lane];

    // epilogue: C/D layout col = lane&15, row = quad*4 + reg.
    // *0.5f compensates the 2.0 bit-encoding (exact, power of two).
#pragma unroll
    for (int j = 0; j < 4; ++j) {
      const int n = n0 + wsub * 64 + j * 16 + l16;
      const float s = rintf(fmaxf(sf[n], 1.0f)) * 0.5f;
#pragma unroll
      for (int i = 0; i < 4; ++i) {
        const int mr = m0 + i * 16 + quad * 4;
#pragma unroll
        for (int r = 0; r < 4; ++r)
          C[(size_t)(mr + r) * NOUT + n] = acc[i][j][r] * s;
      }
    }
  }
}

extern "C" void kernel_launch(void* const* d_in, const int* in_sizes, int n_in,
                              void* d_out, int out_size, void* d_ws, size_t ws_size,
                              hipStream_t stream) {
  const float* x  = (const float*)d_in[0];  // [1024][4096]
  const float* w  = (const float*)d_in[1];  // [4096][4096]
  const float* sf = (const float*)d_in[2];  // [4096]
  float* out = (float*)d_out;               // [1024][4096]

  unsigned short* Bfrag = (unsigned short*)d_ws;                        // 2 MB
  unsigned short* Xfrag = (unsigned short*)((char*)d_ws + (4u << 20));  // 8 MB

  prep_wx<<<6144, 256, 0, stream>>>((const float4*)w, Bfrag, (const float4*)x,
                                    (uint4*)Xfrag);
  gemm_bin_kernel<<<256, 512, 0, stream>>>(Xfrag, Bfrag, sf, out);
}